// Round 13
// baseline (373.679 us; speedup 1.0000x reference)
//
#include <hip/hip_runtime.h>
#include <hip/hip_bf16.h>

constexpr int N_  = 12288;
constexpr int E_  = 393216;
constexpr int IND = 128;
constexpr int HID = 64;
constexpr int QKD = 32;
constexpr int CAP = 96;
constexpr int NBLK = 256;

typedef __attribute__((ext_vector_type(4))) float f4raw;
typedef __attribute__((ext_vector_type(8))) __bf16 bf16x8;
typedef __attribute__((ext_vector_type(4))) __bf16 bf16x4;
typedef __attribute__((ext_vector_type(16))) float f32x16;

__device__ inline bf16x8 lds_read_bf8(const char* base, int row, int k) {
  int off = (row * 128 + k * 2) ^ ((row & 7) << 4);
  uint4 u = *(const uint4*)(base + off);
  union { uint4 u; bf16x8 v; } c; c.u = u; return c.v;
}
__device__ inline void lds_write_bf(char* base, int row, int col, __bf16 v) {
  int off = (row * 128 + col * 2) ^ ((row & 7) << 4);
  *(__bf16*)(base + off) = v;
}

// device-wide software barrier; bar[gen-1]=counter, bar[3]=flag (memset-zeroed each call)
__device__ __forceinline__ void gbar(int* bar, int gen) {
  __syncthreads();
  if (threadIdx.x == 0) {
    __threadfence();  // agent-scope release (L2 writeback)
    int v = __hip_atomic_fetch_add(&bar[gen - 1], 1, __ATOMIC_ACQ_REL, __HIP_MEMORY_SCOPE_AGENT);
    if (v == NBLK - 1) {
      __hip_atomic_store(&bar[3], gen, __ATOMIC_RELEASE, __HIP_MEMORY_SCOPE_AGENT);
    } else {
      while (__hip_atomic_load(&bar[3], __ATOMIC_ACQUIRE, __HIP_MEMORY_SCOPE_AGENT) < gen) {
        __builtin_amdgcn_s_sleep(2);
      }
    }
  }
  __syncthreads();
}

// ================= mega-kernel: P (prep) / E (enc+dinv) / L1 / L2 =================
__global__ __launch_bounds__(512, 2) void mega_kernel(
    const float* __restrict__ xo, const float* __restrict__ xt,
    const int* __restrict__ row, const int* __restrict__ col,
    const float* __restrict__ W1, const float* __restrict__ b1,
    const float* __restrict__ W2, const float* __restrict__ b2,
    const float* __restrict__ Wq, const float* __restrict__ bq,
    const float* __restrict__ Wk, const float* __restrict__ bk,
    const float* __restrict__ Wv, const float* __restrict__ bv,
    const float* __restrict__ Wdx, const float* __restrict__ bdx,
    const unsigned char* __restrict__ mask,
    __bf16* __restrict__ xb, __bf16* __restrict__ W1T, __bf16* __restrict__ W2T,
    __bf16* __restrict__ WvT, __bf16* __restrict__ WdxT,
    float* __restrict__ h_tr, float* __restrict__ dinv, float* __restrict__ lap1d,
    float* __restrict__ xhat, __bf16* __restrict__ zb,
    int* degRow, int* cntCol, int* __restrict__ csrRow, float* gsum, int* bar) {
  __shared__ __align__(16) char smem[2][17408];
  int tid = threadIdx.x;
  int u = tid >> 8, utid = tid & 255;
  int uid = (int)blockIdx.x * 2 + u;
  char* sm = smem[u];

  // ---------------- stage P: hist + bucket scatter + bf16 prep ----------------
  for (int w = uid; w < 2308; w += 512) {
    if (w < 384) {
      int e0 = (w * 256 + utid) * 4;
      int4 r4 = *(const int4*)(row + e0);
      atomicAdd(&degRow[r4.x], 1);
      atomicAdd(&degRow[r4.y], 1);
      atomicAdd(&degRow[r4.z], 1);
      atomicAdd(&degRow[r4.w], 1);
    } else if (w < 768) {
      int e0 = ((w - 384) * 256 + utid) * 4;
      int4 r4 = *(const int4*)(row + e0);
      int4 c4 = *(const int4*)(col + e0);
      int p;
      p = atomicAdd(&cntCol[c4.x], 1); csrRow[c4.x * CAP + p] = r4.x;
      p = atomicAdd(&cntCol[c4.y], 1); csrRow[c4.y * CAP + p] = r4.y;
      p = atomicAdd(&cntCol[c4.z], 1); csrRow[c4.z * CAP + p] = r4.z;
      p = atomicAdd(&cntCol[c4.w], 1); csrRow[c4.w * CAP + p] = r4.w;
    } else if (w < 2304) {
      size_t base = (size_t)(w - 768) * 2048 + (size_t)utid * 8;
      const size_t half = (size_t)N_ * IND;
      const float* src = (base < half) ? (xo + base) : (xt + (base - half));
      f4raw v0 = *(const f4raw*)(src);
      f4raw v1 = *(const f4raw*)(src + 4);
      bf16x8 o;
      o[0] = (__bf16)v0.x; o[1] = (__bf16)v0.y; o[2] = (__bf16)v0.z; o[3] = (__bf16)v0.w;
      o[4] = (__bf16)v1.x; o[5] = (__bf16)v1.y; o[6] = (__bf16)v1.z; o[7] = (__bf16)v1.w;
      *(bf16x8*)(xb + base) = o;
    } else if (w == 2304) {
      for (int e = utid; e < IND * HID; e += 256) {
        int c = e >> 7, k = e & 127;
        W1T[e] = (__bf16)W1[k * HID + c];
      }
    } else if (w == 2305) {
      for (int e = utid; e < HID * HID; e += 256) {
        int c = e >> 6, k = e & 63;
        W2T[e] = (__bf16)W2[k * HID + c];
      }
    } else if (w == 2306) {
      for (int e = utid; e < HID * HID; e += 256) {
        int c = e >> 6, k = e & 63;
        WvT[e] = (__bf16)Wv[k * HID + c];
      }
    } else {
      for (int e = utid; e < HID * IND; e += 256) {
        int c = e >> 6, k = e & 63;
        WdxT[e] = (__bf16)Wdx[k * IND + c];
      }
    }
  }
  gbar(bar, 1);

  // ---------------- stage E: MFMA encoder (+gsum) + dinv ----------------
  {
    const int w = uid;
    const bool act = w < 396;
    const bool isenc = act && (w < 384);
    if (act && !isenc) {
      int i0 = ((w - 384) * 256 + utid) * 4;
      int4 dg = *(const int4*)(degRow + i0);
      f4raw o = {rsqrtf((float)max(dg.x, 1)), rsqrtf((float)max(dg.y, 1)),
                 rsqrtf((float)max(dg.z, 1)), rsqrtf((float)max(dg.w, 1))};
      *(f4raw*)(dinv + i0) = o;
    }
    const bool ori = w < 192;
    const int row0 = (ori ? w : w - 192) * 64;
    float* wls = (float*)(sm + 8192);
    if (isenc && ori && utid < 64) wls[utid] = mask[row0 + utid] ? 0.f : 1.f;
    int wave = utid >> 6, lane = utid & 63;
    int p = wave >> 1, w2 = wave & 1;
    int lr = lane & 31, hi = lane >> 5;
    int colc = w2 * 32 + lr;
    char* h1p = sm + p * 4096;
    if (isenc) {
      const __bf16* xrow = xb + (ori ? (size_t)0 : (size_t)N_ * IND) + (size_t)row0 * IND;
      f32x16 acc = (f32x16)(0.f);
      const __bf16* wcol = W1T + (size_t)colc * IND + hi * 8;
      const __bf16* arow = xrow + (size_t)(p * 32 + lr) * IND + hi * 8;
#pragma unroll
      for (int kk = 0; kk < 8; ++kk) {
        bf16x8 a = *(const bf16x8*)(arow + kk * 16);
        bf16x8 bq = *(const bf16x8*)(wcol + kk * 16);
        acc = __builtin_amdgcn_mfma_f32_32x32x16_bf16(a, bq, acc, 0, 0, 0);
      }
      float b1l = b1[colc];
#pragma unroll
      for (int reg = 0; reg < 16; ++reg) {
        int rr = (reg & 3) + 8 * (reg >> 2) + 4 * hi;
        lds_write_bf(h1p, rr, colc, (__bf16)fmaxf(acc[reg] + b1l, 0.f));
      }
    }
    __syncthreads();
    if (isenc) {
      f32x16 acc2 = (f32x16)(0.f);
      const __bf16* wcol2 = W2T + (size_t)colc * HID + hi * 8;
#pragma unroll
      for (int kk = 0; kk < 4; ++kk) {
        bf16x8 a = lds_read_bf8(h1p, lr, kk * 16 + hi * 8);
        bf16x8 bq = *(const bf16x8*)(wcol2 + kk * 16);
        acc2 = __builtin_amdgcn_mfma_f32_32x32x16_bf16(a, bq, acc2, 0, 0, 0);
      }
      float b2l = b2[colc];
      if (ori) {
        float part = 0.f;
#pragma unroll
        for (int reg = 0; reg < 16; ++reg) {
          int rr = (reg & 3) + 8 * (reg >> 2) + 4 * hi;
          part = fmaf(wls[p * 32 + rr], fmaxf(acc2[reg] + b2l, 0.f), part);
        }
        atomicAdd(&gsum[colc], part);
        if (utid == 0) {
          float wl = 0.f;
          for (int r = 0; r < 64; ++r) wl += wls[r];
          atomicAdd(&gsum[64], wl);
        }
      } else {
#pragma unroll
        for (int reg = 0; reg < 16; ++reg) {
          int rr = (reg & 3) + 8 * (reg >> 2) + 4 * hi;
          h_tr[(size_t)(row0 + p * 32 + rr) * HID + colc] = fmaxf(acc2[reg] + b2l, 0.f);
        }
      }
    }
  }
  gbar(bar, 2);

  // ---------------- stage L1: lap1d = (h - sum(h[r]*dinv[r])*d)*d ----------------
  for (int w = uid; w < 768; w += 512) {
    int lane = utid & 63, wv = utid >> 6;
    int g = lane >> 4, t = lane & 15;
    int c = w * 16 + wv * 4 + g;
    int s0 = c * CAP, s1 = s0 + cntCol[c];
    f4raw a0 = (f4raw)(0.f), a1 = (f4raw)(0.f), a2 = (f4raw)(0.f), a3 = (f4raw)(0.f);
    int i = s0;
    for (; i + 3 < s1; i += 4) {
      int r0 = csrRow[i], r1 = csrRow[i + 1], r2 = csrRow[i + 2], r3 = csrRow[i + 3];
      a0 += (*(const f4raw*)(h_tr + (size_t)r0 * HID + t * 4)) * dinv[r0];
      a1 += (*(const f4raw*)(h_tr + (size_t)r1 * HID + t * 4)) * dinv[r1];
      a2 += (*(const f4raw*)(h_tr + (size_t)r2 * HID + t * 4)) * dinv[r2];
      a3 += (*(const f4raw*)(h_tr + (size_t)r3 * HID + t * 4)) * dinv[r3];
    }
    for (; i < s1; ++i) {
      int r0 = csrRow[i];
      a0 += (*(const f4raw*)(h_tr + (size_t)r0 * HID + t * 4)) * dinv[r0];
    }
    float d = dinv[c];
    size_t idx = (size_t)c * HID + t * 4;
    f4raw hc = *(const f4raw*)(h_tr + idx);
    *(f4raw*)(lap1d + idx) = (hc - ((a0 + a1) + (a2 + a3)) * d) * d;
  }
  gbar(bar, 3);

  // ---------------- stage L2: lap2-gather + qfinal + attn + z + x_hat ----------------
  {
    const int w = uid;
    const bool act = w < 384;
    const int row0 = w * 32;
    float (*l2s)[68] = (float(*)[68])sm;        // 8704 B
    char* zps = sm + 8704;                      // 4096 B
    char* zsl = sm + 12800;                     // 4096 B
    float* qg  = (float*)(sm + 16896);          // 128 B
    float* kqs = (float*)(sm + 17024);          // 288 B
    float wsum = gsum[64];
    if (act && utid < QKD) {
      float inv = 1.0f / fmaxf(wsum, 1.0f);
      float a = bq[utid] * wsum;
      for (int d0 = 0; d0 < HID; ++d0) a = fmaf(gsum[d0], Wq[d0 * QKD + utid], a);
      qg[utid] = a * inv;
    }
    int grp = utid >> 4, t = utid & 15;
    if (act) {
#pragma unroll
      for (int it = 0; it < 2; ++it) {
        int r = grp + 16 * it;
        int c = row0 + r;
        int s0 = c * CAP, s1 = s0 + cntCol[c];
        f4raw a0 = (f4raw)(0.f), a1 = (f4raw)(0.f), a2 = (f4raw)(0.f), a3 = (f4raw)(0.f);
        int i = s0;
        for (; i + 3 < s1; i += 4) {
          int r0 = csrRow[i], r1 = csrRow[i + 1], r2 = csrRow[i + 2], r3 = csrRow[i + 3];
          a0 += *(const f4raw*)(lap1d + (size_t)r0 * HID + t * 4);
          a1 += *(const f4raw*)(lap1d + (size_t)r1 * HID + t * 4);
          a2 += *(const f4raw*)(lap1d + (size_t)r2 * HID + t * 4);
          a3 += *(const f4raw*)(lap1d + (size_t)r3 * HID + t * 4);
        }
        for (; i < s1; ++i) {
          int r0 = csrRow[i];
          a0 += *(const f4raw*)(lap1d + (size_t)r0 * HID + t * 4);
        }
        float d = dinv[c];
        float rd = 1.0f / d;
        f4raw lv = *(const f4raw*)(lap1d + (size_t)c * HID + t * 4);
        *(f4raw*)&l2s[r][t * 4] = lv * rd - ((a0 + a1) + (a2 + a3)) * d;
      }
    }
    __syncthreads();
    if (act) {
      if (utid < 64) {
        float a = 0.f;
        for (int q = 0; q < QKD; ++q) a = fmaf(Wk[utid * QKD + q], qg[q], a);
        kqs[utid] = a * 0.125f;
      } else if (utid == 64) {
        float sb = 0.f;
        for (int q = 0; q < QKD; ++q) sb = fmaf(bk[q], qg[q], sb);
        kqs[64] = sb * 0.125f;
      }
    }
    __syncthreads();
    if (act) {
      f4raw kq4 = *(const f4raw*)(&kqs[t * 4]);
      float sbias = kqs[64];
#pragma unroll
      for (int it = 0; it < 2; ++it) {
        int r = grp + 16 * it;
        int c = row0 + r;
        size_t idx = (size_t)c * HID + t * 4;
        float d = dinv[c];
        float rd = 1.0f / d;
        f4raw hv = *(const f4raw*)(h_tr + idx);
        f4raw v1 = *(const f4raw*)(lap1d + idx) * rd;
        f4raw v2 = *(const f4raw*)&l2s[r][t * 4];
        f4raw av = 2.f * hv - v1;
        float s0 = av.x * kq4.x + av.y * kq4.y + av.z * kq4.z + av.w * kq4.w;
        float s1 = v1.x * kq4.x + v1.y * kq4.y + v1.z * kq4.z + v1.w * kq4.w;
        float s2 = v2.x * kq4.x + v2.y * kq4.y + v2.z * kq4.z + v2.w * kq4.w;
#pragma unroll
        for (int o = 1; o < 16; o <<= 1) {
          s0 += __shfl_xor(s0, o);
          s1 += __shfl_xor(s1, o);
          s2 += __shfl_xor(s2, o);
        }
        s0 += sbias; s1 += sbias; s2 += sbias;
        float m = fmaxf(s0, fmaxf(s1, s2));
        float e0 = __expf(s0 - m), e1 = __expf(s1 - m), e2 = __expf(s2 - m);
        float is = 1.f / (e0 + e1 + e2);
        f4raw zp = (e0 * av + e1 * v1 + e2 * v2) * is;
        bf16x4 z4;
        z4[0] = (__bf16)zp.x; z4[1] = (__bf16)zp.y; z4[2] = (__bf16)zp.z; z4[3] = (__bf16)zp.w;
        int off = (r * 128 + t * 8) ^ ((r & 7) << 4);
        *(bf16x4*)(zps + off) = z4;
      }
    }
    __syncthreads();
    int wave = utid >> 6, lane = utid & 63;
    int lr = lane & 31, hi = lane >> 5;
    if (act && wave < 2) {
      int colz = wave * 32 + lr;
      f32x16 accz = (f32x16)(0.f);
      const __bf16* wv = WvT + (size_t)colz * HID + hi * 8;
#pragma unroll
      for (int kk = 0; kk < 4; ++kk) {
        bf16x8 a = lds_read_bf8(zps, lr, kk * 16 + hi * 8);
        bf16x8 bq = *(const bf16x8*)(wv + kk * 16);
        accz = __builtin_amdgcn_mfma_f32_32x32x16_bf16(a, bq, accz, 0, 0, 0);
      }
      float bvl = bv[colz];
#pragma unroll
      for (int reg = 0; reg < 16; ++reg) {
        int rr = (reg & 3) + 8 * (reg >> 2) + 4 * hi;
        __bf16 vb = (__bf16)(accz[reg] + bvl);
        zb[(size_t)(row0 + rr) * HID + colz] = vb;
        lds_write_bf(zsl, rr, colz, vb);
      }
    }
    __syncthreads();
    if (act) {
      int c0 = wave * 32 + lr;
      f32x16 acx = (f32x16)(0.f);
      const __bf16* wd = WdxT + (size_t)c0 * HID + hi * 8;
#pragma unroll
      for (int kk = 0; kk < 4; ++kk) {
        bf16x8 a = lds_read_bf8(zsl, lr, kk * 16 + hi * 8);
        bf16x8 bq = *(const bf16x8*)(wd + kk * 16);
        acx = __builtin_amdgcn_mfma_f32_32x32x16_bf16(a, bq, acx, 0, 0, 0);
      }
      float bdl = bdx[c0];
#pragma unroll
      for (int reg = 0; reg < 16; ++reg) {
        int rr = (reg & 3) + 8 * (reg >> 2) + 4 * hi;
        xhat[(size_t)(row0 + rr) * IND + c0] = acx[reg] + bdl;
      }
    }
  }
}

// ---------------- adj_hat = z @ z^T via bf16 MFMA (R8 exact) ----------------
__global__ __launch_bounds__(256) void adj_mfma_kernel(
    const __bf16* __restrict__ z, float* __restrict__ out) {
  int tid = threadIdx.x;
  int wave = tid >> 6, lane = tid & 63;
  int wr = wave >> 1, wc = wave & 1;
  int rb = blockIdx.y, cb = blockIdx.x;
  int lr = lane & 31, hi = lane >> 5;

  size_t arow0 = (size_t)(rb * 128 + wr * 64 + lr) * HID;
  size_t arow1 = arow0 + (size_t)32 * HID;
  size_t brow0 = (size_t)(cb * 128 + wc * 64 + lr) * HID;
  size_t brow1 = brow0 + (size_t)32 * HID;
  int kbase = hi * 8;

  f32x16 acc00 = (f32x16)(0.f), acc01 = (f32x16)(0.f);
  f32x16 acc10 = (f32x16)(0.f), acc11 = (f32x16)(0.f);

#pragma unroll
  for (int kk = 0; kk < 4; ++kk) {
    int k0 = kk * 16 + kbase;
    bf16x8 a0 = *(const bf16x8*)(z + arow0 + k0);
    bf16x8 a1 = *(const bf16x8*)(z + arow1 + k0);
    bf16x8 b0 = *(const bf16x8*)(z + brow0 + k0);
    bf16x8 b1 = *(const bf16x8*)(z + brow1 + k0);
    acc00 = __builtin_amdgcn_mfma_f32_32x32x16_bf16(a0, b0, acc00, 0, 0, 0);
    acc01 = __builtin_amdgcn_mfma_f32_32x32x16_bf16(a0, b1, acc01, 0, 0, 0);
    acc10 = __builtin_amdgcn_mfma_f32_32x32x16_bf16(a1, b0, acc10, 0, 0, 0);
    acc11 = __builtin_amdgcn_mfma_f32_32x32x16_bf16(a1, b1, acc11, 0, 0, 0);
  }

  int colb = cb * 128 + wc * 64 + lr;
  int rowb = rb * 128 + wr * 64 + 4 * hi;
#pragma unroll
  for (int reg = 0; reg < 16; ++reg) {
    int rr = (reg & 3) + 8 * (reg >> 2);
    size_t r0 = (size_t)(rowb + rr);
    __builtin_nontemporal_store(acc00[reg], out + r0 * N_ + colb);
    __builtin_nontemporal_store(acc01[reg], out + r0 * N_ + colb + 32);
    __builtin_nontemporal_store(acc10[reg], out + (r0 + 32) * N_ + colb);
    __builtin_nontemporal_store(acc11[reg], out + (r0 + 32) * N_ + colb + 32);
  }
}

extern "C" void kernel_launch(void* const* d_in, const int* in_sizes, int n_in,
                              void* d_out, int out_size, void* d_ws, size_t ws_size,
                              hipStream_t stream) {
  const float* x_train = (const float*)d_in[0];
  const float* x_ori   = (const float*)d_in[1];
  const int*   ei      = (const int*)d_in[2];
  const unsigned char* mask = (const unsigned char*)d_in[3];
  const float* W1  = (const float*)d_in[4];
  const float* b1  = (const float*)d_in[5];
  const float* W2  = (const float*)d_in[6];
  const float* b2  = (const float*)d_in[7];
  const float* Wq  = (const float*)d_in[8];
  const float* bq  = (const float*)d_in[9];
  const float* Wk  = (const float*)d_in[10];
  const float* bk  = (const float*)d_in[11];
  const float* Wv  = (const float*)d_in[12];
  const float* bv  = (const float*)d_in[13];
  const float* Wdx = (const float*)d_in[14];
  const float* bdx = (const float*)d_in[15];

  char* ws = (char*)d_ws;
  size_t o = 0;
  auto alloc = [&](size_t bytes) -> void* {
    void* p = ws + o;
    o += (bytes + 255) & ~(size_t)255;
    return p;
  };
  __bf16* xb    = (__bf16*)alloc((size_t)2 * N_ * IND * 2);
  __bf16* W1T   = (__bf16*)alloc((size_t)IND * HID * 2);
  __bf16* W2T   = (__bf16*)alloc((size_t)HID * HID * 2);
  __bf16* WvT   = (__bf16*)alloc((size_t)HID * HID * 2);
  __bf16* WdxT  = (__bf16*)alloc((size_t)HID * IND * 2);
  float* h_tr   = (float*)alloc((size_t)N_ * HID * 4);
  float* lap1d  = (float*)alloc((size_t)N_ * HID * 4);
  __bf16* zb    = (__bf16*)alloc((size_t)N_ * HID * 2);
  float* dinv   = (float*)alloc((size_t)N_ * 4);
  int*   csrRow = (int*)alloc((size_t)N_ * CAP * 4);
  int*   zero0  = (int*)alloc((size_t)(2 * N_ + 65 + 8) * 4);
  int*   degRow = zero0;
  int*   cntCol = zero0 + N_;
  float* gsum   = (float*)(zero0 + 2 * N_);
  int*   bar    = zero0 + 2 * N_ + 65;

  const int* row = ei;
  const int* col = ei + E_;

  (void)hipMemsetAsync(zero0, 0, (size_t)(2 * N_ + 65 + 8) * 4, stream);

  float* outp = (float*)d_out;
  mega_kernel<<<NBLK, 512, 0, stream>>>(x_ori, x_train, row, col,
                                        W1, b1, W2, b2, Wq, bq, Wk, bk,
                                        Wv, bv, Wdx, bdx, mask,
                                        xb, W1T, W2T, WvT, WdxT,
                                        h_tr, dinv, lap1d, outp, zb,
                                        degRow, cntCol, csrRow, gsum, bar);
  adj_mfma_kernel<<<dim3(96, 96), 256, 0, stream>>>(zb, outp + (size_t)N_ * IND);
}

// Round 14
// 247.846 us; speedup vs baseline: 1.5077x; 1.5077x over previous
//
#include <hip/hip_runtime.h>
#include <hip/hip_bf16.h>

constexpr int N_  = 12288;
constexpr int E_  = 393216;
constexpr int IND = 128;
constexpr int HID = 64;
constexpr int QKD = 32;
constexpr int CAP = 96;   // bucket capacity per node (mean deg 32, sigma 5.7)

typedef __attribute__((ext_vector_type(4))) float f4raw;
typedef __attribute__((ext_vector_type(8))) __bf16 bf16x8;
typedef __attribute__((ext_vector_type(4))) __bf16 bf16x4;
typedef __attribute__((ext_vector_type(16))) float f32x16;

// LDS bf16 tile helpers: rows of 128 B, XOR-swizzled (byte ^= (row&7)<<4).
__device__ inline bf16x8 lds_read_bf8(const char* base, int row, int k) {
  int off = (row * 128 + k * 2) ^ ((row & 7) << 4);
  uint4 u = *(const uint4*)(base + off);
  union { uint4 u; bf16x8 v; } c; c.u = u; return c.v;
}
__device__ inline void lds_write_bf(char* base, int row, int col, __bf16 v) {
  int off = (row * 128 + col * 2) ^ ((row & 7) << 4);
  *(__bf16*)(base + off) = v;
}

// ---------------- K1: degRow hist + direct bucket scatter + weight prep ----------------
// blocks [0,384): hist, [384,768): scatter, 768..771: weight transposes.
__global__ __launch_bounds__(256) void prep_graph_kernel(
    const int* __restrict__ row, const int* __restrict__ col,
    const float* __restrict__ W1, const float* __restrict__ W2,
    const float* __restrict__ Wv, const float* __restrict__ Wdx,
    __bf16* __restrict__ W1T, __bf16* __restrict__ W2T,
    __bf16* __restrict__ WvT, __bf16* __restrict__ WdxT,
    int* degRow, int* cntCol, int* __restrict__ csrRow) {
  int b = blockIdx.x, tid = threadIdx.x;
  if (b < 384) {
    int e0 = (b * 256 + tid) * 4;
    int4 r4 = *(const int4*)(row + e0);
    atomicAdd(&degRow[r4.x], 1);
    atomicAdd(&degRow[r4.y], 1);
    atomicAdd(&degRow[r4.z], 1);
    atomicAdd(&degRow[r4.w], 1);
  } else if (b < 768) {
    int e0 = ((b - 384) * 256 + tid) * 4;
    int4 r4 = *(const int4*)(row + e0);
    int4 c4 = *(const int4*)(col + e0);
    int p;
    p = atomicAdd(&cntCol[c4.x], 1); csrRow[c4.x * CAP + p] = r4.x;
    p = atomicAdd(&cntCol[c4.y], 1); csrRow[c4.y * CAP + p] = r4.y;
    p = atomicAdd(&cntCol[c4.z], 1); csrRow[c4.z * CAP + p] = r4.z;
    p = atomicAdd(&cntCol[c4.w], 1); csrRow[c4.w * CAP + p] = r4.w;
  } else if (b == 768) {
    for (int e = tid; e < IND * HID; e += 256) {
      int c = e >> 7, k = e & 127;
      W1T[e] = (__bf16)W1[k * HID + c];
    }
  } else if (b == 769) {
    for (int e = tid; e < HID * HID; e += 256) {
      int c = e >> 6, k = e & 63;
      W2T[e] = (__bf16)W2[k * HID + c];
    }
  } else if (b == 770) {
    for (int e = tid; e < HID * HID; e += 256) {
      int c = e >> 6, k = e & 63;
      WvT[e] = (__bf16)Wv[k * HID + c];
    }
  } else {
    for (int e = tid; e < HID * IND; e += 256) {
      int c = e >> 6, k = e & 63;
      WdxT[e] = (__bf16)Wdx[k * IND + c];
    }
  }
}

// ---------------- K2: MFMA encoder (fp32 x, in-register bf16 cast) + gsum + dinv ----------------
__global__ __launch_bounds__(256) void enc_dinv_kernel(
    const float* __restrict__ xo, const float* __restrict__ xt,
    const __bf16* __restrict__ W1T, const float* __restrict__ b1,
    const __bf16* __restrict__ W2T, const float* __restrict__ b2,
    const int* __restrict__ degRow, const unsigned char* __restrict__ mask,
    float* __restrict__ h_tr, float* __restrict__ dinv, float* __restrict__ gsum) {
  __shared__ __align__(16) char h1s[2][32 * 128];
  __shared__ float wls[64];
  int b = blockIdx.x, tid = threadIdx.x;
  if (b >= 384) {
    int i0 = ((b - 384) * 256 + tid) * 4;
    int4 dg = *(const int4*)(degRow + i0);
    f4raw o = {rsqrtf((float)max(dg.x, 1)), rsqrtf((float)max(dg.y, 1)),
               rsqrtf((float)max(dg.z, 1)), rsqrtf((float)max(dg.w, 1))};
    *(f4raw*)(dinv + i0) = o;
    return;
  }
  bool ori = b < 192;
  int row0 = (ori ? b : b - 192) * 64;
  const float* xrow = (ori ? xo : xt) + (size_t)row0 * IND;
  if (ori && tid < 64) wls[tid] = mask[row0 + tid] ? 0.f : 1.f;
  int wave = tid >> 6, lane = tid & 63;
  int p = wave >> 1, w2 = wave & 1;
  int lr = lane & 31, hi = lane >> 5;
  int colc = w2 * 32 + lr;
  f32x16 acc = (f32x16)(0.f);
  const __bf16* wcol = W1T + (size_t)colc * IND + hi * 8;
  const float* arow = xrow + (size_t)(p * 32 + lr) * IND + hi * 8;
#pragma unroll
  for (int kk = 0; kk < 8; ++kk) {
    f4raw v0 = *(const f4raw*)(arow + kk * 16);
    f4raw v1 = *(const f4raw*)(arow + kk * 16 + 4);
    bf16x8 a;
    a[0] = (__bf16)v0.x; a[1] = (__bf16)v0.y; a[2] = (__bf16)v0.z; a[3] = (__bf16)v0.w;
    a[4] = (__bf16)v1.x; a[5] = (__bf16)v1.y; a[6] = (__bf16)v1.z; a[7] = (__bf16)v1.w;
    bf16x8 bq = *(const bf16x8*)(wcol + kk * 16);
    acc = __builtin_amdgcn_mfma_f32_32x32x16_bf16(a, bq, acc, 0, 0, 0);
  }
  float b1l = b1[colc];
#pragma unroll
  for (int reg = 0; reg < 16; ++reg) {
    int rr = (reg & 3) + 8 * (reg >> 2) + 4 * hi;
    float v = fmaxf(acc[reg] + b1l, 0.f);
    lds_write_bf(h1s[p], rr, colc, (__bf16)v);
  }
  __syncthreads();
  f32x16 acc2 = (f32x16)(0.f);
  const __bf16* wcol2 = W2T + (size_t)colc * HID + hi * 8;
#pragma unroll
  for (int kk = 0; kk < 4; ++kk) {
    bf16x8 a = lds_read_bf8(h1s[p], lr, kk * 16 + hi * 8);
    bf16x8 bq = *(const bf16x8*)(wcol2 + kk * 16);
    acc2 = __builtin_amdgcn_mfma_f32_32x32x16_bf16(a, bq, acc2, 0, 0, 0);
  }
  float b2l = b2[colc];
  if (ori) {
    float part = 0.f;
#pragma unroll
    for (int reg = 0; reg < 16; ++reg) {
      int rr = (reg & 3) + 8 * (reg >> 2) + 4 * hi;
      float v = fmaxf(acc2[reg] + b2l, 0.f);
      part = fmaf(wls[p * 32 + rr], v, part);
    }
    atomicAdd(&gsum[colc], part);
    if (tid == 0) {
      float wl = 0.f;
      for (int r = 0; r < 64; ++r) wl += wls[r];
      atomicAdd(&gsum[64], wl);
    }
  } else {
#pragma unroll
    for (int reg = 0; reg < 16; ++reg) {
      int rr = (reg & 3) + 8 * (reg >> 2) + 4 * hi;
      float v = fmaxf(acc2[reg] + b2l, 0.f);
      h_tr[(size_t)(row0 + p * 32 + rr) * HID + colc] = v;
    }
  }
}

// ---------------- K3: lap1d = (h - sum(h[r]*dinv[r])*d)*d, 4-deep unroll ----------------
__global__ __launch_bounds__(256) void lap1_kernel(
    const float* __restrict__ h, const float* __restrict__ dinv,
    const int* __restrict__ cnt, const int* __restrict__ csrRow,
    float* __restrict__ lap1d) {
  int lane = threadIdx.x & 63, wv = threadIdx.x >> 6;
  int g = lane >> 4, t = lane & 15;
  int c = blockIdx.x * 16 + wv * 4 + g;
  int s0 = c * CAP, s1 = s0 + cnt[c];
  f4raw a0 = (f4raw)(0.f), a1 = (f4raw)(0.f), a2 = (f4raw)(0.f), a3 = (f4raw)(0.f);
  int i = s0;
  for (; i + 3 < s1; i += 4) {
    int r0 = csrRow[i], r1 = csrRow[i + 1], r2 = csrRow[i + 2], r3 = csrRow[i + 3];
    a0 += (*(const f4raw*)(h + (size_t)r0 * HID + t * 4)) * dinv[r0];
    a1 += (*(const f4raw*)(h + (size_t)r1 * HID + t * 4)) * dinv[r1];
    a2 += (*(const f4raw*)(h + (size_t)r2 * HID + t * 4)) * dinv[r2];
    a3 += (*(const f4raw*)(h + (size_t)r3 * HID + t * 4)) * dinv[r3];
  }
  for (; i < s1; ++i) {
    int r0 = csrRow[i];
    a0 += (*(const f4raw*)(h + (size_t)r0 * HID + t * 4)) * dinv[r0];
  }
  float d = dinv[c];
  size_t idx = (size_t)c * HID + t * 4;
  f4raw hc = *(const f4raw*)(h + idx);
  *(f4raw*)(lap1d + idx) = (hc - ((a0 + a1) + (a2 + a3)) * d) * d;
}

// ---------------- K4: lap2-gather + qfinal + attention + z=zp@Wv+bv + x_hat ----------------
__global__ __launch_bounds__(256) void lap2_attnz_xhat_kernel(
    const float* __restrict__ h, const float* __restrict__ lap1d,
    const float* __restrict__ dinv,
    const int* __restrict__ cnt, const int* __restrict__ csrRow,
    const float* __restrict__ gsum,
    const float* __restrict__ Wq, const float* __restrict__ bq,
    const float* __restrict__ Wk, const float* __restrict__ bk,
    const __bf16* __restrict__ WvT, const float* __restrict__ bv,
    const __bf16* __restrict__ WdxT, const float* __restrict__ bdx,
    float* __restrict__ xhat, __bf16* __restrict__ zb) {
  __shared__ float l2s[32][68];
  __shared__ __align__(16) char zps[32 * 128];
  __shared__ __align__(16) char zsl[32 * 128];
  __shared__ float qg[QKD];
  __shared__ float kqs[72];
  int tid = threadIdx.x;
  int row0 = blockIdx.x * 32;
  float wsum = gsum[64];
  if (tid < QKD) {
    float inv = 1.0f / fmaxf(wsum, 1.0f);
    float a = bq[tid] * wsum;
    for (int d0 = 0; d0 < HID; ++d0) a = fmaf(gsum[d0], Wq[d0 * QKD + tid], a);
    qg[tid] = a * inv;
  }
  int grp = tid >> 4, t = tid & 15;
#pragma unroll
  for (int it = 0; it < 2; ++it) {
    int r = grp + 16 * it;
    int c = row0 + r;
    int s0 = c * CAP, s1 = s0 + cnt[c];
    f4raw a0 = (f4raw)(0.f), a1 = (f4raw)(0.f), a2 = (f4raw)(0.f), a3 = (f4raw)(0.f);
    int i = s0;
    for (; i + 3 < s1; i += 4) {
      int r0 = csrRow[i], r1 = csrRow[i + 1], r2 = csrRow[i + 2], r3 = csrRow[i + 3];
      a0 += *(const f4raw*)(lap1d + (size_t)r0 * HID + t * 4);
      a1 += *(const f4raw*)(lap1d + (size_t)r1 * HID + t * 4);
      a2 += *(const f4raw*)(lap1d + (size_t)r2 * HID + t * 4);
      a3 += *(const f4raw*)(lap1d + (size_t)r3 * HID + t * 4);
    }
    for (; i < s1; ++i) {
      int r0 = csrRow[i];
      a0 += *(const f4raw*)(lap1d + (size_t)r0 * HID + t * 4);
    }
    float d = dinv[c];
    float rd = 1.0f / d;
    f4raw lv = *(const f4raw*)(lap1d + (size_t)c * HID + t * 4);
    *(f4raw*)&l2s[r][t * 4] = lv * rd - ((a0 + a1) + (a2 + a3)) * d;
  }
  __syncthreads();
  if (tid < 64) {
    float a = 0.f;
    for (int q = 0; q < QKD; ++q) a = fmaf(Wk[tid * QKD + q], qg[q], a);
    kqs[tid] = a * 0.125f;
  } else if (tid == 64) {
    float sb = 0.f;
    for (int q = 0; q < QKD; ++q) sb = fmaf(bk[q], qg[q], sb);
    kqs[64] = sb * 0.125f;
  }
  __syncthreads();
  f4raw kq4 = *(const f4raw*)(&kqs[t * 4]);
  float sbias = kqs[64];
#pragma unroll
  for (int it = 0; it < 2; ++it) {
    int r = grp + 16 * it;
    int c = row0 + r;
    size_t idx = (size_t)c * HID + t * 4;
    float d = dinv[c];
    float rd = 1.0f / d;
    f4raw hv = *(const f4raw*)(h + idx);
    f4raw v1 = *(const f4raw*)(lap1d + idx) * rd;
    f4raw v2 = *(const f4raw*)&l2s[r][t * 4];
    f4raw av = 2.f * hv - v1;
    float s0 = av.x * kq4.x + av.y * kq4.y + av.z * kq4.z + av.w * kq4.w;
    float s1 = v1.x * kq4.x + v1.y * kq4.y + v1.z * kq4.z + v1.w * kq4.w;
    float s2 = v2.x * kq4.x + v2.y * kq4.y + v2.z * kq4.z + v2.w * kq4.w;
#pragma unroll
    for (int o = 1; o < 16; o <<= 1) {
      s0 += __shfl_xor(s0, o);
      s1 += __shfl_xor(s1, o);
      s2 += __shfl_xor(s2, o);
    }
    s0 += sbias; s1 += sbias; s2 += sbias;
    float m = fmaxf(s0, fmaxf(s1, s2));
    float e0 = __expf(s0 - m), e1 = __expf(s1 - m), e2 = __expf(s2 - m);
    float is = 1.f / (e0 + e1 + e2);
    f4raw zp = (e0 * av + e1 * v1 + e2 * v2) * is;
    bf16x4 z4;
    z4[0] = (__bf16)zp.x; z4[1] = (__bf16)zp.y; z4[2] = (__bf16)zp.z; z4[3] = (__bf16)zp.w;
    int off = (r * 128 + t * 8) ^ ((r & 7) << 4);
    *(bf16x4*)(zps + off) = z4;
  }
  __syncthreads();
  int wave = tid >> 6, lane = tid & 63;
  int lr = lane & 31, hi = lane >> 5;
  if (wave < 2) {
    int col = wave * 32 + lr;
    f32x16 accz = (f32x16)(0.f);
    const __bf16* wv = WvT + (size_t)col * HID + hi * 8;
#pragma unroll
    for (int kk = 0; kk < 4; ++kk) {
      bf16x8 a = lds_read_bf8(zps, lr, kk * 16 + hi * 8);
      bf16x8 bq = *(const bf16x8*)(wv + kk * 16);
      accz = __builtin_amdgcn_mfma_f32_32x32x16_bf16(a, bq, accz, 0, 0, 0);
    }
    float bvl = bv[col];
#pragma unroll
    for (int reg = 0; reg < 16; ++reg) {
      int rr = (reg & 3) + 8 * (reg >> 2) + 4 * hi;
      __bf16 vb = (__bf16)(accz[reg] + bvl);
      zb[(size_t)(row0 + rr) * HID + col] = vb;
      lds_write_bf(zsl, rr, col, vb);
    }
  }
  __syncthreads();
  {
    int c0 = wave * 32 + lr;
    f32x16 acx = (f32x16)(0.f);
    const __bf16* wd = WdxT + (size_t)c0 * HID + hi * 8;
#pragma unroll
    for (int kk = 0; kk < 4; ++kk) {
      bf16x8 a = lds_read_bf8(zsl, lr, kk * 16 + hi * 8);
      bf16x8 bq = *(const bf16x8*)(wd + kk * 16);
      acx = __builtin_amdgcn_mfma_f32_32x32x16_bf16(a, bq, acx, 0, 0, 0);
    }
    float bdl = bdx[c0];
#pragma unroll
    for (int reg = 0; reg < 16; ++reg) {
      int rr = (reg & 3) + 8 * (reg >> 2) + 4 * hi;
      xhat[(size_t)(row0 + rr) * IND + c0] = acx[reg] + bdl;
    }
  }
}

// ---------------- K5: adj_hat = z @ z^T via bf16 MFMA (R8 exact) ----------------
__global__ __launch_bounds__(256) void adj_mfma_kernel(
    const __bf16* __restrict__ z, float* __restrict__ out) {
  int tid = threadIdx.x;
  int wave = tid >> 6, lane = tid & 63;
  int wr = wave >> 1, wc = wave & 1;
  int rb = blockIdx.y, cb = blockIdx.x;
  int lr = lane & 31, hi = lane >> 5;

  size_t arow0 = (size_t)(rb * 128 + wr * 64 + lr) * HID;
  size_t arow1 = arow0 + (size_t)32 * HID;
  size_t brow0 = (size_t)(cb * 128 + wc * 64 + lr) * HID;
  size_t brow1 = brow0 + (size_t)32 * HID;
  int kbase = hi * 8;

  f32x16 acc00 = (f32x16)(0.f), acc01 = (f32x16)(0.f);
  f32x16 acc10 = (f32x16)(0.f), acc11 = (f32x16)(0.f);

#pragma unroll
  for (int kk = 0; kk < 4; ++kk) {
    int k0 = kk * 16 + kbase;
    bf16x8 a0 = *(const bf16x8*)(z + arow0 + k0);
    bf16x8 a1 = *(const bf16x8*)(z + arow1 + k0);
    bf16x8 b0 = *(const bf16x8*)(z + brow0 + k0);
    bf16x8 b1 = *(const bf16x8*)(z + brow1 + k0);
    acc00 = __builtin_amdgcn_mfma_f32_32x32x16_bf16(a0, b0, acc00, 0, 0, 0);
    acc01 = __builtin_amdgcn_mfma_f32_32x32x16_bf16(a0, b1, acc01, 0, 0, 0);
    acc10 = __builtin_amdgcn_mfma_f32_32x32x16_bf16(a1, b0, acc10, 0, 0, 0);
    acc11 = __builtin_amdgcn_mfma_f32_32x32x16_bf16(a1, b1, acc11, 0, 0, 0);
  }

  int colb = cb * 128 + wc * 64 + lr;
  int rowb = rb * 128 + wr * 64 + 4 * hi;
#pragma unroll
  for (int reg = 0; reg < 16; ++reg) {
    int rr = (reg & 3) + 8 * (reg >> 2);
    size_t r0 = (size_t)(rowb + rr);
    __builtin_nontemporal_store(acc00[reg], out + r0 * N_ + colb);
    __builtin_nontemporal_store(acc01[reg], out + r0 * N_ + colb + 32);
    __builtin_nontemporal_store(acc10[reg], out + (r0 + 32) * N_ + colb);
    __builtin_nontemporal_store(acc11[reg], out + (r0 + 32) * N_ + colb + 32);
  }
}

extern "C" void kernel_launch(void* const* d_in, const int* in_sizes, int n_in,
                              void* d_out, int out_size, void* d_ws, size_t ws_size,
                              hipStream_t stream) {
  const float* x_train = (const float*)d_in[0];
  const float* x_ori   = (const float*)d_in[1];
  const int*   ei      = (const int*)d_in[2];
  const unsigned char* mask = (const unsigned char*)d_in[3];
  const float* W1  = (const float*)d_in[4];
  const float* b1  = (const float*)d_in[5];
  const float* W2  = (const float*)d_in[6];
  const float* b2  = (const float*)d_in[7];
  const float* Wq  = (const float*)d_in[8];
  const float* bq  = (const float*)d_in[9];
  const float* Wk  = (const float*)d_in[10];
  const float* bk  = (const float*)d_in[11];
  const float* Wv  = (const float*)d_in[12];
  const float* bv  = (const float*)d_in[13];
  const float* Wdx = (const float*)d_in[14];
  const float* bdx = (const float*)d_in[15];

  char* ws = (char*)d_ws;
  size_t o = 0;
  auto alloc = [&](size_t bytes) -> void* {
    void* p = ws + o;
    o += (bytes + 255) & ~(size_t)255;
    return p;
  };
  __bf16* W1T   = (__bf16*)alloc((size_t)IND * HID * 2);
  __bf16* W2T   = (__bf16*)alloc((size_t)HID * HID * 2);
  __bf16* WvT   = (__bf16*)alloc((size_t)HID * HID * 2);
  __bf16* WdxT  = (__bf16*)alloc((size_t)HID * IND * 2);
  float* h_tr   = (float*)alloc((size_t)N_ * HID * 4);
  float* lap1d  = (float*)alloc((size_t)N_ * HID * 4);
  __bf16* zb    = (__bf16*)alloc((size_t)N_ * HID * 2);
  float* dinv   = (float*)alloc((size_t)N_ * 4);
  int*   csrRow = (int*)alloc((size_t)N_ * CAP * 4);
  int*   zero0  = (int*)alloc((size_t)(2 * N_ + 65) * 4);
  int*   degRow = zero0;
  int*   cntCol = zero0 + N_;
  float* gsum   = (float*)(zero0 + 2 * N_);

  const int* row = ei;
  const int* col = ei + E_;

  (void)hipMemsetAsync(zero0, 0, (size_t)(2 * N_ + 65) * 4, stream);

  prep_graph_kernel<<<772, 256, 0, stream>>>(row, col, W1, W2, Wv, Wdx,
                                             W1T, W2T, WvT, WdxT,
                                             degRow, cntCol, csrRow);
  enc_dinv_kernel<<<396, 256, 0, stream>>>(x_ori, x_train, W1T, b1, W2T, b2,
                                           degRow, mask, h_tr, dinv, gsum);
  lap1_kernel<<<N_ / 16, 256, 0, stream>>>(h_tr, dinv, cntCol, csrRow, lap1d);

  float* outp = (float*)d_out;
  lap2_attnz_xhat_kernel<<<N_ / 32, 256, 0, stream>>>(h_tr, lap1d, dinv,
                                                      cntCol, csrRow, gsum,
                                                      Wq, bq, Wk, bk, WvT, bv,
                                                      WdxT, bdx, outp, zb);
  adj_mfma_kernel<<<dim3(96, 96), 256, 0, stream>>>(zb, outp + (size_t)N_ * IND);
}

// Round 15
// 239.163 us; speedup vs baseline: 1.5624x; 1.0363x over previous
//
#include <hip/hip_runtime.h>
#include <hip/hip_bf16.h>

constexpr int N_  = 12288;
constexpr int E_  = 393216;
constexpr int IND = 128;
constexpr int HID = 64;
constexpr int QKD = 32;
constexpr int CAP = 96;   // bucket capacity per node (mean deg 32, sigma 5.7)

typedef __attribute__((ext_vector_type(4))) float f4raw;
typedef __attribute__((ext_vector_type(8))) __bf16 bf16x8;
typedef __attribute__((ext_vector_type(4))) __bf16 bf16x4;
typedef __attribute__((ext_vector_type(16))) float f32x16;

// LDS bf16 tile helpers, 128B rows, XOR-swizzled (byte ^= (row&7)<<4).
__device__ inline bf16x8 lds_read_bf8(const char* base, int row, int k) {
  int off = (row * 128 + k * 2) ^ ((row & 7) << 4);
  uint4 u = *(const uint4*)(base + off);
  union { uint4 u; bf16x8 v; } c; c.u = u; return c.v;
}
__device__ inline void lds_write_bf(char* base, int row, int col, __bf16 v) {
  int off = (row * 128 + col * 2) ^ ((row & 7) << 4);
  *(__bf16*)(base + off) = v;
}
// 256B-row variants (for [64][128] bf16 W1 tile)
__device__ inline bf16x8 lds_read_bf8_256(const char* base, int row, int k) {
  int off = (row * 256 + k * 2) ^ ((row & 7) << 4);
  uint4 u = *(const uint4*)(base + off);
  union { uint4 u; bf16x8 v; } c; c.u = u; return c.v;
}
__device__ inline void lds_write_bf_256(char* base, int row, int col, __bf16 v) {
  int off = (row * 256 + col * 2) ^ ((row & 7) << 4);
  *(__bf16*)(base + off) = v;
}

// ---------------- K12: hist || scatter || WvT/WdxT prep || MFMA encoder ----------------
// blocks [0,384): hist; [384,768): scatter; 768/769: WvT/WdxT; [770,1154): encoder.
// Legal single-dispatch fusion: the paths share NO data (encoder stages W1/W2 itself).
__global__ __launch_bounds__(256) void fused_front_kernel(
    const float* __restrict__ xo, const float* __restrict__ xt,
    const int* __restrict__ row, const int* __restrict__ col,
    const float* __restrict__ W1, const float* __restrict__ b1,
    const float* __restrict__ W2, const float* __restrict__ b2,
    const float* __restrict__ Wv, const float* __restrict__ Wdx,
    const unsigned char* __restrict__ mask,
    __bf16* __restrict__ WvT, __bf16* __restrict__ WdxT,
    float* __restrict__ h_tr, float* __restrict__ gsum,
    int* degRow, int* cntCol, int* __restrict__ csrRow) {
  __shared__ __align__(16) char W1s[16384];     // [64 c][128 k] bf16, 256B rows
  __shared__ __align__(16) char W2s[8192];      // [64 c][64 k]  bf16, 128B rows
  __shared__ __align__(16) char h1s[2][4096];
  __shared__ float wls[64];
  int b = blockIdx.x, tid = threadIdx.x;
  if (b < 384) {
    int e0 = (b * 256 + tid) * 4;
    int4 r4 = *(const int4*)(row + e0);
    atomicAdd(&degRow[r4.x], 1);
    atomicAdd(&degRow[r4.y], 1);
    atomicAdd(&degRow[r4.z], 1);
    atomicAdd(&degRow[r4.w], 1);
    return;
  }
  if (b < 768) {
    int e0 = ((b - 384) * 256 + tid) * 4;
    int4 r4 = *(const int4*)(row + e0);
    int4 c4 = *(const int4*)(col + e0);
    int p;
    p = atomicAdd(&cntCol[c4.x], 1); csrRow[c4.x * CAP + p] = r4.x;
    p = atomicAdd(&cntCol[c4.y], 1); csrRow[c4.y * CAP + p] = r4.y;
    p = atomicAdd(&cntCol[c4.z], 1); csrRow[c4.z * CAP + p] = r4.z;
    p = atomicAdd(&cntCol[c4.w], 1); csrRow[c4.w * CAP + p] = r4.w;
    return;
  }
  if (b == 768) {
    for (int e = tid; e < HID * HID; e += 256) {
      int c = e >> 6, k = e & 63;
      WvT[e] = (__bf16)Wv[k * HID + c];
    }
    return;
  }
  if (b == 769) {
    for (int e = tid; e < HID * IND; e += 256) {
      int c = e >> 6, k = e & 63;
      WdxT[e] = (__bf16)Wdx[k * IND + c];
    }
    return;
  }
  // ---------------- encoder ----------------
  int bb = b - 770;
  bool ori = bb < 192;
  int row0 = (ori ? bb : bb - 192) * 64;
  const float* xrow = (ori ? xo : xt) + (size_t)row0 * IND;
  // stage W1, W2 -> LDS transposed bf16 (coalesced global reads; swizzled LDS writes)
  for (int e = tid; e < IND * HID; e += 256) {
    int k = e >> 6, c = e & 63;                 // W1[e] = W1[k][c]
    lds_write_bf_256(W1s, c, k, (__bf16)W1[e]);
  }
  for (int e = tid; e < HID * HID; e += 256) {
    int k = e >> 6, c = e & 63;
    lds_write_bf(W2s, c, k, (__bf16)W2[e]);
  }
  if (ori && tid < 64) wls[tid] = mask[row0 + tid] ? 0.f : 1.f;
  __syncthreads();
  int wave = tid >> 6, lane = tid & 63;
  int p = wave >> 1, w2 = wave & 1;
  int lr = lane & 31, hi = lane >> 5;
  int colc = w2 * 32 + lr;
  f32x16 acc = (f32x16)(0.f);
  const float* arow = xrow + (size_t)(p * 32 + lr) * IND + hi * 8;
#pragma unroll
  for (int kk = 0; kk < 8; ++kk) {
    f4raw v0 = *(const f4raw*)(arow + kk * 16);
    f4raw v1 = *(const f4raw*)(arow + kk * 16 + 4);
    bf16x8 a;
    a[0] = (__bf16)v0.x; a[1] = (__bf16)v0.y; a[2] = (__bf16)v0.z; a[3] = (__bf16)v0.w;
    a[4] = (__bf16)v1.x; a[5] = (__bf16)v1.y; a[6] = (__bf16)v1.z; a[7] = (__bf16)v1.w;
    bf16x8 bq = lds_read_bf8_256(W1s, colc, kk * 16 + hi * 8);
    acc = __builtin_amdgcn_mfma_f32_32x32x16_bf16(a, bq, acc, 0, 0, 0);
  }
  float b1l = b1[colc];
#pragma unroll
  for (int reg = 0; reg < 16; ++reg) {
    int rr = (reg & 3) + 8 * (reg >> 2) + 4 * hi;
    float v = fmaxf(acc[reg] + b1l, 0.f);
    lds_write_bf(h1s[p], rr, colc, (__bf16)v);
  }
  __syncthreads();
  f32x16 acc2 = (f32x16)(0.f);
#pragma unroll
  for (int kk = 0; kk < 4; ++kk) {
    bf16x8 a = lds_read_bf8(h1s[p], lr, kk * 16 + hi * 8);
    bf16x8 bq = lds_read_bf8(W2s, colc, kk * 16 + hi * 8);
    acc2 = __builtin_amdgcn_mfma_f32_32x32x16_bf16(a, bq, acc2, 0, 0, 0);
  }
  float b2l = b2[colc];
  if (ori) {
    float part = 0.f;
#pragma unroll
    for (int reg = 0; reg < 16; ++reg) {
      int rr = (reg & 3) + 8 * (reg >> 2) + 4 * hi;
      float v = fmaxf(acc2[reg] + b2l, 0.f);
      part = fmaf(wls[p * 32 + rr], v, part);
    }
    atomicAdd(&gsum[colc], part);
    if (tid == 0) {
      float wl = 0.f;
      for (int r = 0; r < 64; ++r) wl += wls[r];
      atomicAdd(&gsum[64], wl);
    }
  } else {
#pragma unroll
    for (int reg = 0; reg < 16; ++reg) {
      int rr = (reg & 3) + 8 * (reg >> 2) + 4 * hi;
      float v = fmaxf(acc2[reg] + b2l, 0.f);
      h_tr[(size_t)(row0 + p * 32 + rr) * HID + colc] = v;
    }
  }
}

// ---------------- K3: lap1d = (h - sum(h[r]*dinv[r])*d)*d ; emits dinv ----------------
__global__ __launch_bounds__(256) void lap1_kernel(
    const float* __restrict__ h, const int* __restrict__ degRow,
    const int* __restrict__ cnt, const int* __restrict__ csrRow,
    float* __restrict__ lap1d, float* __restrict__ dinv) {
  int lane = threadIdx.x & 63, wv = threadIdx.x >> 6;
  int g = lane >> 4, t = lane & 15;
  int c = blockIdx.x * 16 + wv * 4 + g;
  int s0 = c * CAP, s1 = s0 + cnt[c];
  f4raw a0 = (f4raw)(0.f), a1 = (f4raw)(0.f), a2 = (f4raw)(0.f), a3 = (f4raw)(0.f);
  int i = s0;
  for (; i + 3 < s1; i += 4) {
    int r0 = csrRow[i], r1 = csrRow[i + 1], r2 = csrRow[i + 2], r3 = csrRow[i + 3];
    float d0 = rsqrtf((float)max(degRow[r0], 1));
    float d1 = rsqrtf((float)max(degRow[r1], 1));
    float d2 = rsqrtf((float)max(degRow[r2], 1));
    float d3 = rsqrtf((float)max(degRow[r3], 1));
    a0 += (*(const f4raw*)(h + (size_t)r0 * HID + t * 4)) * d0;
    a1 += (*(const f4raw*)(h + (size_t)r1 * HID + t * 4)) * d1;
    a2 += (*(const f4raw*)(h + (size_t)r2 * HID + t * 4)) * d2;
    a3 += (*(const f4raw*)(h + (size_t)r3 * HID + t * 4)) * d3;
  }
  for (; i < s1; ++i) {
    int r0 = csrRow[i];
    float d0 = rsqrtf((float)max(degRow[r0], 1));
    a0 += (*(const f4raw*)(h + (size_t)r0 * HID + t * 4)) * d0;
  }
  float d = rsqrtf((float)max(degRow[c], 1));
  if (t == 0) dinv[c] = d;
  size_t idx = (size_t)c * HID + t * 4;
  f4raw hc = *(const f4raw*)(h + idx);
  *(f4raw*)(lap1d + idx) = (hc - ((a0 + a1) + (a2 + a3)) * d) * d;
}

// ---------------- K4: lap2-gather + qfinal + attention + z=zp@Wv+bv + x_hat ----------------
__global__ __launch_bounds__(256) void lap2_attnz_xhat_kernel(
    const float* __restrict__ h, const float* __restrict__ lap1d,
    const float* __restrict__ dinv,
    const int* __restrict__ cnt, const int* __restrict__ csrRow,
    const float* __restrict__ gsum,
    const float* __restrict__ Wq, const float* __restrict__ bq,
    const float* __restrict__ Wk, const float* __restrict__ bk,
    const __bf16* __restrict__ WvT, const float* __restrict__ bv,
    const __bf16* __restrict__ WdxT, const float* __restrict__ bdx,
    float* __restrict__ xhat, __bf16* __restrict__ zb) {
  __shared__ float l2s[32][68];
  __shared__ __align__(16) char zps[32 * 128];
  __shared__ __align__(16) char zsl[32 * 128];
  __shared__ float qg[QKD];
  __shared__ float kqs[72];
  int tid = threadIdx.x;
  int row0 = blockIdx.x * 32;
  float wsum = gsum[64];
  if (tid < QKD) {
    float inv = 1.0f / fmaxf(wsum, 1.0f);
    float a = bq[tid] * wsum;
    for (int d0 = 0; d0 < HID; ++d0) a = fmaf(gsum[d0], Wq[d0 * QKD + tid], a);
    qg[tid] = a * inv;
  }
  int grp = tid >> 4, t = tid & 15;
#pragma unroll
  for (int it = 0; it < 2; ++it) {
    int r = grp + 16 * it;
    int c = row0 + r;
    int s0 = c * CAP, s1 = s0 + cnt[c];
    f4raw a0 = (f4raw)(0.f), a1 = (f4raw)(0.f), a2 = (f4raw)(0.f), a3 = (f4raw)(0.f);
    int i = s0;
    for (; i + 3 < s1; i += 4) {
      int r0 = csrRow[i], r1 = csrRow[i + 1], r2 = csrRow[i + 2], r3 = csrRow[i + 3];
      a0 += *(const f4raw*)(lap1d + (size_t)r0 * HID + t * 4);
      a1 += *(const f4raw*)(lap1d + (size_t)r1 * HID + t * 4);
      a2 += *(const f4raw*)(lap1d + (size_t)r2 * HID + t * 4);
      a3 += *(const f4raw*)(lap1d + (size_t)r3 * HID + t * 4);
    }
    for (; i < s1; ++i) {
      int r0 = csrRow[i];
      a0 += *(const f4raw*)(lap1d + (size_t)r0 * HID + t * 4);
    }
    float d = dinv[c];
    float rd = 1.0f / d;
    f4raw lv = *(const f4raw*)(lap1d + (size_t)c * HID + t * 4);
    *(f4raw*)&l2s[r][t * 4] = lv * rd - ((a0 + a1) + (a2 + a3)) * d;
  }
  __syncthreads();
  if (tid < 64) {
    float a = 0.f;
    for (int q = 0; q < QKD; ++q) a = fmaf(Wk[tid * QKD + q], qg[q], a);
    kqs[tid] = a * 0.125f;
  } else if (tid == 64) {
    float sb = 0.f;
    for (int q = 0; q < QKD; ++q) sb = fmaf(bk[q], qg[q], sb);
    kqs[64] = sb * 0.125f;
  }
  __syncthreads();
  f4raw kq4 = *(const f4raw*)(&kqs[t * 4]);
  float sbias = kqs[64];
#pragma unroll
  for (int it = 0; it < 2; ++it) {
    int r = grp + 16 * it;
    int c = row0 + r;
    size_t idx = (size_t)c * HID + t * 4;
    float d = dinv[c];
    float rd = 1.0f / d;
    f4raw hv = *(const f4raw*)(h + idx);
    f4raw v1 = *(const f4raw*)(lap1d + idx) * rd;
    f4raw v2 = *(const f4raw*)&l2s[r][t * 4];
    f4raw av = 2.f * hv - v1;
    float s0 = av.x * kq4.x + av.y * kq4.y + av.z * kq4.z + av.w * kq4.w;
    float s1 = v1.x * kq4.x + v1.y * kq4.y + v1.z * kq4.z + v1.w * kq4.w;
    float s2 = v2.x * kq4.x + v2.y * kq4.y + v2.z * kq4.z + v2.w * kq4.w;
#pragma unroll
    for (int o = 1; o < 16; o <<= 1) {
      s0 += __shfl_xor(s0, o);
      s1 += __shfl_xor(s1, o);
      s2 += __shfl_xor(s2, o);
    }
    s0 += sbias; s1 += sbias; s2 += sbias;
    float m = fmaxf(s0, fmaxf(s1, s2));
    float e0 = __expf(s0 - m), e1 = __expf(s1 - m), e2 = __expf(s2 - m);
    float is = 1.f / (e0 + e1 + e2);
    f4raw zp = (e0 * av + e1 * v1 + e2 * v2) * is;
    bf16x4 z4;
    z4[0] = (__bf16)zp.x; z4[1] = (__bf16)zp.y; z4[2] = (__bf16)zp.z; z4[3] = (__bf16)zp.w;
    int off = (r * 128 + t * 8) ^ ((r & 7) << 4);
    *(bf16x4*)(zps + off) = z4;
  }
  __syncthreads();
  int wave = tid >> 6, lane = tid & 63;
  int lr = lane & 31, hi = lane >> 5;
  if (wave < 2) {
    int col = wave * 32 + lr;
    f32x16 accz = (f32x16)(0.f);
    const __bf16* wv = WvT + (size_t)col * HID + hi * 8;
#pragma unroll
    for (int kk = 0; kk < 4; ++kk) {
      bf16x8 a = lds_read_bf8(zps, lr, kk * 16 + hi * 8);
      bf16x8 bq = *(const bf16x8*)(wv + kk * 16);
      accz = __builtin_amdgcn_mfma_f32_32x32x16_bf16(a, bq, accz, 0, 0, 0);
    }
    float bvl = bv[col];
#pragma unroll
    for (int reg = 0; reg < 16; ++reg) {
      int rr = (reg & 3) + 8 * (reg >> 2) + 4 * hi;
      __bf16 vb = (__bf16)(accz[reg] + bvl);
      zb[(size_t)(row0 + rr) * HID + col] = vb;
      lds_write_bf(zsl, rr, col, vb);
    }
  }
  __syncthreads();
  {
    int c0 = wave * 32 + lr;
    f32x16 acx = (f32x16)(0.f);
    const __bf16* wd = WdxT + (size_t)c0 * HID + hi * 8;
#pragma unroll
    for (int kk = 0; kk < 4; ++kk) {
      bf16x8 a = lds_read_bf8(zsl, lr, kk * 16 + hi * 8);
      bf16x8 bq = *(const bf16x8*)(wd + kk * 16);
      acx = __builtin_amdgcn_mfma_f32_32x32x16_bf16(a, bq, acx, 0, 0, 0);
    }
    float bdl = bdx[c0];
#pragma unroll
    for (int reg = 0; reg < 16; ++reg) {
      int rr = (reg & 3) + 8 * (reg >> 2) + 4 * hi;
      xhat[(size_t)(row0 + rr) * IND + c0] = acx[reg] + bdl;
    }
  }
}

// ---------------- K5: adj_hat = z @ z^T via bf16 MFMA (R8 exact) ----------------
__global__ __launch_bounds__(256) void adj_mfma_kernel(
    const __bf16* __restrict__ z, float* __restrict__ out) {
  int tid = threadIdx.x;
  int wave = tid >> 6, lane = tid & 63;
  int wr = wave >> 1, wc = wave & 1;
  int rb = blockIdx.y, cb = blockIdx.x;
  int lr = lane & 31, hi = lane >> 5;

  size_t arow0 = (size_t)(rb * 128 + wr * 64 + lr) * HID;
  size_t arow1 = arow0 + (size_t)32 * HID;
  size_t brow0 = (size_t)(cb * 128 + wc * 64 + lr) * HID;
  size_t brow1 = brow0 + (size_t)32 * HID;
  int kbase = hi * 8;

  f32x16 acc00 = (f32x16)(0.f), acc01 = (f32x16)(0.f);
  f32x16 acc10 = (f32x16)(0.f), acc11 = (f32x16)(0.f);

#pragma unroll
  for (int kk = 0; kk < 4; ++kk) {
    int k0 = kk * 16 + kbase;
    bf16x8 a0 = *(const bf16x8*)(z + arow0 + k0);
    bf16x8 a1 = *(const bf16x8*)(z + arow1 + k0);
    bf16x8 b0 = *(const bf16x8*)(z + brow0 + k0);
    bf16x8 b1 = *(const bf16x8*)(z + brow1 + k0);
    acc00 = __builtin_amdgcn_mfma_f32_32x32x16_bf16(a0, b0, acc00, 0, 0, 0);
    acc01 = __builtin_amdgcn_mfma_f32_32x32x16_bf16(a0, b1, acc01, 0, 0, 0);
    acc10 = __builtin_amdgcn_mfma_f32_32x32x16_bf16(a1, b0, acc10, 0, 0, 0);
    acc11 = __builtin_amdgcn_mfma_f32_32x32x16_bf16(a1, b1, acc11, 0, 0, 0);
  }

  int colb = cb * 128 + wc * 64 + lr;
  int rowb = rb * 128 + wr * 64 + 4 * hi;
#pragma unroll
  for (int reg = 0; reg < 16; ++reg) {
    int rr = (reg & 3) + 8 * (reg >> 2);
    size_t r0 = (size_t)(rowb + rr);
    __builtin_nontemporal_store(acc00[reg], out + r0 * N_ + colb);
    __builtin_nontemporal_store(acc01[reg], out + r0 * N_ + colb + 32);
    __builtin_nontemporal_store(acc10[reg], out + (r0 + 32) * N_ + colb);
    __builtin_nontemporal_store(acc11[reg], out + (r0 + 32) * N_ + colb + 32);
  }
}

extern "C" void kernel_launch(void* const* d_in, const int* in_sizes, int n_in,
                              void* d_out, int out_size, void* d_ws, size_t ws_size,
                              hipStream_t stream) {
  const float* x_train = (const float*)d_in[0];
  const float* x_ori   = (const float*)d_in[1];
  const int*   ei      = (const int*)d_in[2];
  const unsigned char* mask = (const unsigned char*)d_in[3];
  const float* W1  = (const float*)d_in[4];
  const float* b1  = (const float*)d_in[5];
  const float* W2  = (const float*)d_in[6];
  const float* b2  = (const float*)d_in[7];
  const float* Wq  = (const float*)d_in[8];
  const float* bq  = (const float*)d_in[9];
  const float* Wk  = (const float*)d_in[10];
  const float* bk  = (const float*)d_in[11];
  const float* Wv  = (const float*)d_in[12];
  const float* bv  = (const float*)d_in[13];
  const float* Wdx = (const float*)d_in[14];
  const float* bdx = (const float*)d_in[15];

  char* ws = (char*)d_ws;
  size_t o = 0;
  auto alloc = [&](size_t bytes) -> void* {
    void* p = ws + o;
    o += (bytes + 255) & ~(size_t)255;
    return p;
  };
  __bf16* WvT   = (__bf16*)alloc((size_t)HID * HID * 2);
  __bf16* WdxT  = (__bf16*)alloc((size_t)HID * IND * 2);
  float* h_tr   = (float*)alloc((size_t)N_ * HID * 4);
  float* lap1d  = (float*)alloc((size_t)N_ * HID * 4);
  __bf16* zb    = (__bf16*)alloc((size_t)N_ * HID * 2);
  float* dinv   = (float*)alloc((size_t)N_ * 4);
  int*   csrRow = (int*)alloc((size_t)N_ * CAP * 4);
  int*   zero0  = (int*)alloc((size_t)(2 * N_ + 65) * 4);
  int*   degRow = zero0;
  int*   cntCol = zero0 + N_;
  float* gsum   = (float*)(zero0 + 2 * N_);

  const int* row = ei;
  const int* col = ei + E_;

  (void)hipMemsetAsync(zero0, 0, (size_t)(2 * N_ + 65) * 4, stream);

  fused_front_kernel<<<1154, 256, 0, stream>>>(x_ori, x_train, row, col,
                                               W1, b1, W2, b2, Wv, Wdx, mask,
                                               WvT, WdxT, h_tr, gsum,
                                               degRow, cntCol, csrRow);
  lap1_kernel<<<N_ / 16, 256, 0, stream>>>(h_tr, degRow, cntCol, csrRow,
                                           lap1d, dinv);

  float* outp = (float*)d_out;
  lap2_attnz_xhat_kernel<<<N_ / 32, 256, 0, stream>>>(h_tr, lap1d, dinv,
                                                      cntCol, csrRow, gsum,
                                                      Wq, bq, Wk, bk, WvT, bv,
                                                      WdxT, bdx, outp, zb);
  adj_mfma_kernel<<<dim3(96, 96), 256, 0, stream>>>(zb, outp + (size_t)N_ * IND);
}

// Round 16
// 232.176 us; speedup vs baseline: 1.6095x; 1.0301x over previous
//
#include <hip/hip_runtime.h>
#include <hip/hip_bf16.h>

constexpr int N_  = 12288;
constexpr int E_  = 393216;
constexpr int IND = 128;
constexpr int HID = 64;
constexpr int QKD = 32;
constexpr int CAP = 96;   // bucket capacity per node (mean deg 32, sigma 5.7)

typedef __attribute__((ext_vector_type(4))) float f4raw;
typedef __attribute__((ext_vector_type(8))) __bf16 bf16x8;
typedef __attribute__((ext_vector_type(4))) __bf16 bf16x4;
typedef __attribute__((ext_vector_type(16))) float f32x16;

// LDS bf16 tile helpers, 128B rows, XOR-swizzled (byte ^= (row&7)<<4).
__device__ inline bf16x8 lds_read_bf8(const char* base, int row, int k) {
  int off = (row * 128 + k * 2) ^ ((row & 7) << 4);
  uint4 u = *(const uint4*)(base + off);
  union { uint4 u; bf16x8 v; } c; c.u = u; return c.v;
}
__device__ inline void lds_write_bf(char* base, int row, int col, __bf16 v) {
  int off = (row * 128 + col * 2) ^ ((row & 7) << 4);
  *(__bf16*)(base + off) = v;
}
// 256B-row variants (for [64][128] bf16 W1 tile)
__device__ inline bf16x8 lds_read_bf8_256(const char* base, int row, int k) {
  int off = (row * 256 + k * 2) ^ ((row & 7) << 4);
  uint4 u = *(const uint4*)(base + off);
  union { uint4 u; bf16x8 v; } c; c.u = u; return c.v;
}
__device__ inline void lds_write_bf_256(char* base, int row, int col, __bf16 v) {
  int off = (row * 256 + col * 2) ^ ((row & 7) << 4);
  *(__bf16*)(base + off) = v;
}

// ---------------- K12: hist || scatter || WvT/WdxT prep || MFMA encoder ----------------
__global__ __launch_bounds__(256) void fused_front_kernel(
    const float* __restrict__ xo, const float* __restrict__ xt,
    const int* __restrict__ row, const int* __restrict__ col,
    const float* __restrict__ W1, const float* __restrict__ b1,
    const float* __restrict__ W2, const float* __restrict__ b2,
    const float* __restrict__ Wv, const float* __restrict__ Wdx,
    const unsigned char* __restrict__ mask,
    __bf16* __restrict__ WvT, __bf16* __restrict__ WdxT,
    float* __restrict__ h_tr, float* __restrict__ gsum,
    int* degRow, int* cntCol, int* __restrict__ csrRow) {
  __shared__ __align__(16) char W1s[16384];     // [64 c][128 k] bf16, 256B rows
  __shared__ __align__(16) char W2s[8192];      // [64 c][64 k]  bf16, 128B rows
  __shared__ __align__(16) char h1s[2][4096];
  __shared__ float wls[64];
  int b = blockIdx.x, tid = threadIdx.x;
  if (b < 384) {
    int e0 = (b * 256 + tid) * 4;
    int4 r4 = *(const int4*)(row + e0);
    atomicAdd(&degRow[r4.x], 1);
    atomicAdd(&degRow[r4.y], 1);
    atomicAdd(&degRow[r4.z], 1);
    atomicAdd(&degRow[r4.w], 1);
    return;
  }
  if (b < 768) {
    int e0 = ((b - 384) * 256 + tid) * 4;
    int4 r4 = *(const int4*)(row + e0);
    int4 c4 = *(const int4*)(col + e0);
    int p;
    p = atomicAdd(&cntCol[c4.x], 1); csrRow[c4.x * CAP + p] = r4.x;
    p = atomicAdd(&cntCol[c4.y], 1); csrRow[c4.y * CAP + p] = r4.y;
    p = atomicAdd(&cntCol[c4.z], 1); csrRow[c4.z * CAP + p] = r4.z;
    p = atomicAdd(&cntCol[c4.w], 1); csrRow[c4.w * CAP + p] = r4.w;
    return;
  }
  if (b == 768) {
    for (int e = tid; e < HID * HID; e += 256) {
      int c = e >> 6, k = e & 63;
      WvT[e] = (__bf16)Wv[k * HID + c];
    }
    return;
  }
  if (b == 769) {
    for (int e = tid; e < HID * IND; e += 256) {
      int c = e >> 6, k = e & 63;
      WdxT[e] = (__bf16)Wdx[k * IND + c];
    }
    return;
  }
  // ---------------- encoder ----------------
  int bb = b - 770;
  bool ori = bb < 192;
  int row0 = (ori ? bb : bb - 192) * 64;
  const float* xrow = (ori ? xo : xt) + (size_t)row0 * IND;
  for (int e = tid; e < IND * HID; e += 256) {
    int k = e >> 6, c = e & 63;                 // W1[e] = W1[k][c]
    lds_write_bf_256(W1s, c, k, (__bf16)W1[e]);
  }
  for (int e = tid; e < HID * HID; e += 256) {
    int k = e >> 6, c = e & 63;
    lds_write_bf(W2s, c, k, (__bf16)W2[e]);
  }
  if (ori && tid < 64) wls[tid] = mask[row0 + tid] ? 0.f : 1.f;
  __syncthreads();
  int wave = tid >> 6, lane = tid & 63;
  int p = wave >> 1, w2 = wave & 1;
  int lr = lane & 31, hi = lane >> 5;
  int colc = w2 * 32 + lr;
  f32x16 acc = (f32x16)(0.f);
  const float* arow = xrow + (size_t)(p * 32 + lr) * IND + hi * 8;
#pragma unroll
  for (int kk = 0; kk < 8; ++kk) {
    f4raw v0 = *(const f4raw*)(arow + kk * 16);
    f4raw v1 = *(const f4raw*)(arow + kk * 16 + 4);
    bf16x8 a;
    a[0] = (__bf16)v0.x; a[1] = (__bf16)v0.y; a[2] = (__bf16)v0.z; a[3] = (__bf16)v0.w;
    a[4] = (__bf16)v1.x; a[5] = (__bf16)v1.y; a[6] = (__bf16)v1.z; a[7] = (__bf16)v1.w;
    bf16x8 bq = lds_read_bf8_256(W1s, colc, kk * 16 + hi * 8);
    acc = __builtin_amdgcn_mfma_f32_32x32x16_bf16(a, bq, acc, 0, 0, 0);
  }
  float b1l = b1[colc];
#pragma unroll
  for (int reg = 0; reg < 16; ++reg) {
    int rr = (reg & 3) + 8 * (reg >> 2) + 4 * hi;
    float v = fmaxf(acc[reg] + b1l, 0.f);
    lds_write_bf(h1s[p], rr, colc, (__bf16)v);
  }
  __syncthreads();
  f32x16 acc2 = (f32x16)(0.f);
#pragma unroll
  for (int kk = 0; kk < 4; ++kk) {
    bf16x8 a = lds_read_bf8(h1s[p], lr, kk * 16 + hi * 8);
    bf16x8 bq = lds_read_bf8(W2s, colc, kk * 16 + hi * 8);
    acc2 = __builtin_amdgcn_mfma_f32_32x32x16_bf16(a, bq, acc2, 0, 0, 0);
  }
  float b2l = b2[colc];
  if (ori) {
    float part = 0.f;
#pragma unroll
    for (int reg = 0; reg < 16; ++reg) {
      int rr = (reg & 3) + 8 * (reg >> 2) + 4 * hi;
      float v = fmaxf(acc2[reg] + b2l, 0.f);
      part = fmaf(wls[p * 32 + rr], v, part);
    }
    atomicAdd(&gsum[colc], part);
    if (tid == 0) {
      float wl = 0.f;
      for (int r = 0; r < 64; ++r) wl += wls[r];
      atomicAdd(&gsum[64], wl);
    }
  } else {
#pragma unroll
    for (int reg = 0; reg < 16; ++reg) {
      int rr = (reg & 3) + 8 * (reg >> 2) + 4 * hi;
      float v = fmaxf(acc2[reg] + b2l, 0.f);
      h_tr[(size_t)(row0 + p * 32 + rr) * HID + colc] = v;
    }
  }
}

// ---------------- K3: lap1d = (h - sum(h[r]*dinv[r])*d)*d ; emits dinv ----------------
__global__ __launch_bounds__(256) void lap1_kernel(
    const float* __restrict__ h, const int* __restrict__ degRow,
    const int* __restrict__ cnt, const int* __restrict__ csrRow,
    float* __restrict__ lap1d, float* __restrict__ dinv) {
  int lane = threadIdx.x & 63, wv = threadIdx.x >> 6;
  int g = lane >> 4, t = lane & 15;
  int c = blockIdx.x * 16 + wv * 4 + g;
  int s0 = c * CAP, s1 = s0 + cnt[c];
  f4raw a0 = (f4raw)(0.f), a1 = (f4raw)(0.f), a2 = (f4raw)(0.f), a3 = (f4raw)(0.f);
  int i = s0;
  for (; i + 3 < s1; i += 4) {
    int r0 = csrRow[i], r1 = csrRow[i + 1], r2 = csrRow[i + 2], r3 = csrRow[i + 3];
    float d0 = rsqrtf((float)max(degRow[r0], 1));
    float d1 = rsqrtf((float)max(degRow[r1], 1));
    float d2 = rsqrtf((float)max(degRow[r2], 1));
    float d3 = rsqrtf((float)max(degRow[r3], 1));
    a0 += (*(const f4raw*)(h + (size_t)r0 * HID + t * 4)) * d0;
    a1 += (*(const f4raw*)(h + (size_t)r1 * HID + t * 4)) * d1;
    a2 += (*(const f4raw*)(h + (size_t)r2 * HID + t * 4)) * d2;
    a3 += (*(const f4raw*)(h + (size_t)r3 * HID + t * 4)) * d3;
  }
  for (; i < s1; ++i) {
    int r0 = csrRow[i];
    float d0 = rsqrtf((float)max(degRow[r0], 1));
    a0 += (*(const f4raw*)(h + (size_t)r0 * HID + t * 4)) * d0;
  }
  float d = rsqrtf((float)max(degRow[c], 1));
  if (t == 0) dinv[c] = d;
  size_t idx = (size_t)c * HID + t * 4;
  f4raw hc = *(const f4raw*)(h + idx);
  *(f4raw*)(lap1d + idx) = (hc - ((a0 + a1) + (a2 + a3)) * d) * d;
}

// ---------------- K4: lap2-gather + qfinal + attention + z=zp@Wv+bv + x_hat ----------------
// 512 threads (8 waves): 32 gather groups -> 1 node each (was 2 serial).
// Phase B: waves 0-1; phase C: waves 0-3; waves 4-7 idle through MFMA phases.
__global__ __launch_bounds__(512) void lap2_attnz_xhat_kernel(
    const float* __restrict__ h, const float* __restrict__ lap1d,
    const float* __restrict__ dinv,
    const int* __restrict__ cnt, const int* __restrict__ csrRow,
    const float* __restrict__ gsum,
    const float* __restrict__ Wq, const float* __restrict__ bq,
    const float* __restrict__ Wk, const float* __restrict__ bk,
    const __bf16* __restrict__ WvT, const float* __restrict__ bv,
    const __bf16* __restrict__ WdxT, const float* __restrict__ bdx,
    float* __restrict__ xhat, __bf16* __restrict__ zb) {
  __shared__ float l2s[32][68];
  __shared__ __align__(16) char zps[32 * 128];
  __shared__ __align__(16) char zsl[32 * 128];
  __shared__ float qg[QKD];
  __shared__ float kqs[72];
  int tid = threadIdx.x;
  int row0 = blockIdx.x * 32;
  float wsum = gsum[64];
  if (tid < QKD) {
    float inv = 1.0f / fmaxf(wsum, 1.0f);
    float a = bq[tid] * wsum;
    for (int d0 = 0; d0 < HID; ++d0) a = fmaf(gsum[d0], Wq[d0 * QKD + tid], a);
    qg[tid] = a * inv;
  }
  int grp = tid >> 4, t = tid & 15;   // 32 groups x 16 lanes
  {
    int r = grp;
    int c = row0 + r;
    int s0 = c * CAP, s1 = s0 + cnt[c];
    f4raw a0 = (f4raw)(0.f), a1 = (f4raw)(0.f), a2 = (f4raw)(0.f), a3 = (f4raw)(0.f);
    int i = s0;
    for (; i + 3 < s1; i += 4) {
      int r0 = csrRow[i], r1 = csrRow[i + 1], r2 = csrRow[i + 2], r3 = csrRow[i + 3];
      a0 += *(const f4raw*)(lap1d + (size_t)r0 * HID + t * 4);
      a1 += *(const f4raw*)(lap1d + (size_t)r1 * HID + t * 4);
      a2 += *(const f4raw*)(lap1d + (size_t)r2 * HID + t * 4);
      a3 += *(const f4raw*)(lap1d + (size_t)r3 * HID + t * 4);
    }
    for (; i < s1; ++i) {
      int r0 = csrRow[i];
      a0 += *(const f4raw*)(lap1d + (size_t)r0 * HID + t * 4);
    }
    float d = dinv[c];
    float rd = 1.0f / d;
    f4raw lv = *(const f4raw*)(lap1d + (size_t)c * HID + t * 4);
    *(f4raw*)&l2s[r][t * 4] = lv * rd - ((a0 + a1) + (a2 + a3)) * d;
  }
  __syncthreads();
  if (tid < 64) {
    float a = 0.f;
    for (int q = 0; q < QKD; ++q) a = fmaf(Wk[tid * QKD + q], qg[q], a);
    kqs[tid] = a * 0.125f;
  } else if (tid == 64) {
    float sb = 0.f;
    for (int q = 0; q < QKD; ++q) sb = fmaf(bk[q], qg[q], sb);
    kqs[64] = sb * 0.125f;
  }
  __syncthreads();
  {
    f4raw kq4 = *(const f4raw*)(&kqs[t * 4]);
    float sbias = kqs[64];
    int r = grp;
    int c = row0 + r;
    size_t idx = (size_t)c * HID + t * 4;
    float d = dinv[c];
    float rd = 1.0f / d;
    f4raw hv = *(const f4raw*)(h + idx);
    f4raw v1 = *(const f4raw*)(lap1d + idx) * rd;
    f4raw v2 = *(const f4raw*)&l2s[r][t * 4];
    f4raw av = 2.f * hv - v1;
    float s0 = av.x * kq4.x + av.y * kq4.y + av.z * kq4.z + av.w * kq4.w;
    float s1 = v1.x * kq4.x + v1.y * kq4.y + v1.z * kq4.z + v1.w * kq4.w;
    float s2 = v2.x * kq4.x + v2.y * kq4.y + v2.z * kq4.z + v2.w * kq4.w;
#pragma unroll
    for (int o = 1; o < 16; o <<= 1) {
      s0 += __shfl_xor(s0, o);
      s1 += __shfl_xor(s1, o);
      s2 += __shfl_xor(s2, o);
    }
    s0 += sbias; s1 += sbias; s2 += sbias;
    float m = fmaxf(s0, fmaxf(s1, s2));
    float e0 = __expf(s0 - m), e1 = __expf(s1 - m), e2 = __expf(s2 - m);
    float is = 1.f / (e0 + e1 + e2);
    f4raw zp = (e0 * av + e1 * v1 + e2 * v2) * is;
    bf16x4 z4;
    z4[0] = (__bf16)zp.x; z4[1] = (__bf16)zp.y; z4[2] = (__bf16)zp.z; z4[3] = (__bf16)zp.w;
    int off = (r * 128 + t * 8) ^ ((r & 7) << 4);
    *(bf16x4*)(zps + off) = z4;
  }
  __syncthreads();
  int wave = tid >> 6, lane = tid & 63;
  int lr = lane & 31, hi = lane >> 5;
  if (wave < 2) {
    int col = wave * 32 + lr;
    f32x16 accz = (f32x16)(0.f);
    const __bf16* wv = WvT + (size_t)col * HID + hi * 8;
#pragma unroll
    for (int kk = 0; kk < 4; ++kk) {
      bf16x8 a = lds_read_bf8(zps, lr, kk * 16 + hi * 8);
      bf16x8 bq = *(const bf16x8*)(wv + kk * 16);
      accz = __builtin_amdgcn_mfma_f32_32x32x16_bf16(a, bq, accz, 0, 0, 0);
    }
    float bvl = bv[col];
#pragma unroll
    for (int reg = 0; reg < 16; ++reg) {
      int rr = (reg & 3) + 8 * (reg >> 2) + 4 * hi;
      __bf16 vb = (__bf16)(accz[reg] + bvl);
      zb[(size_t)(row0 + rr) * HID + col] = vb;
      lds_write_bf(zsl, rr, col, vb);
    }
  }
  __syncthreads();
  if (wave < 4) {
    int c0 = wave * 32 + lr;
    f32x16 acx = (f32x16)(0.f);
    const __bf16* wd = WdxT + (size_t)c0 * HID + hi * 8;
#pragma unroll
    for (int kk = 0; kk < 4; ++kk) {
      bf16x8 a = lds_read_bf8(zsl, lr, kk * 16 + hi * 8);
      bf16x8 bq = *(const bf16x8*)(wd + kk * 16);
      acx = __builtin_amdgcn_mfma_f32_32x32x16_bf16(a, bq, acx, 0, 0, 0);
    }
    float bdl = bdx[c0];
#pragma unroll
    for (int reg = 0; reg < 16; ++reg) {
      int rr = (reg & 3) + 8 * (reg >> 2) + 4 * hi;
      xhat[(size_t)(row0 + rr) * IND + c0] = acx[reg] + bdl;
    }
  }
}

// ---------------- K5: adj_hat = z @ z^T via bf16 MFMA (R8 exact) ----------------
__global__ __launch_bounds__(256) void adj_mfma_kernel(
    const __bf16* __restrict__ z, float* __restrict__ out) {
  int tid = threadIdx.x;
  int wave = tid >> 6, lane = tid & 63;
  int wr = wave >> 1, wc = wave & 1;
  int rb = blockIdx.y, cb = blockIdx.x;
  int lr = lane & 31, hi = lane >> 5;

  size_t arow0 = (size_t)(rb * 128 + wr * 64 + lr) * HID;
  size_t arow1 = arow0 + (size_t)32 * HID;
  size_t brow0 = (size_t)(cb * 128 + wc * 64 + lr) * HID;
  size_t brow1 = brow0 + (size_t)32 * HID;
  int kbase = hi * 8;

  f32x16 acc00 = (f32x16)(0.f), acc01 = (f32x16)(0.f);
  f32x16 acc10 = (f32x16)(0.f), acc11 = (f32x16)(0.f);

#pragma unroll
  for (int kk = 0; kk < 4; ++kk) {
    int k0 = kk * 16 + kbase;
    bf16x8 a0 = *(const bf16x8*)(z + arow0 + k0);
    bf16x8 a1 = *(const bf16x8*)(z + arow1 + k0);
    bf16x8 b0 = *(const bf16x8*)(z + brow0 + k0);
    bf16x8 b1 = *(const bf16x8*)(z + brow1 + k0);
    acc00 = __builtin_amdgcn_mfma_f32_32x32x16_bf16(a0, b0, acc00, 0, 0, 0);
    acc01 = __builtin_amdgcn_mfma_f32_32x32x16_bf16(a0, b1, acc01, 0, 0, 0);
    acc10 = __builtin_amdgcn_mfma_f32_32x32x16_bf16(a1, b0, acc10, 0, 0, 0);
    acc11 = __builtin_amdgcn_mfma_f32_32x32x16_bf16(a1, b1, acc11, 0, 0, 0);
  }

  int colb = cb * 128 + wc * 64 + lr;
  int rowb = rb * 128 + wr * 64 + 4 * hi;
#pragma unroll
  for (int reg = 0; reg < 16; ++reg) {
    int rr = (reg & 3) + 8 * (reg >> 2);
    size_t r0 = (size_t)(rowb + rr);
    __builtin_nontemporal_store(acc00[reg], out + r0 * N_ + colb);
    __builtin_nontemporal_store(acc01[reg], out + r0 * N_ + colb + 32);
    __builtin_nontemporal_store(acc10[reg], out + (r0 + 32) * N_ + colb);
    __builtin_nontemporal_store(acc11[reg], out + (r0 + 32) * N_ + colb + 32);
  }
}

extern "C" void kernel_launch(void* const* d_in, const int* in_sizes, int n_in,
                              void* d_out, int out_size, void* d_ws, size_t ws_size,
                              hipStream_t stream) {
  const float* x_train = (const float*)d_in[0];
  const float* x_ori   = (const float*)d_in[1];
  const int*   ei      = (const int*)d_in[2];
  const unsigned char* mask = (const unsigned char*)d_in[3];
  const float* W1  = (const float*)d_in[4];
  const float* b1  = (const float*)d_in[5];
  const float* W2  = (const float*)d_in[6];
  const float* b2  = (const float*)d_in[7];
  const float* Wq  = (const float*)d_in[8];
  const float* bq  = (const float*)d_in[9];
  const float* Wk  = (const float*)d_in[10];
  const float* bk  = (const float*)d_in[11];
  const float* Wv  = (const float*)d_in[12];
  const float* bv  = (const float*)d_in[13];
  const float* Wdx = (const float*)d_in[14];
  const float* bdx = (const float*)d_in[15];

  char* ws = (char*)d_ws;
  size_t o = 0;
  auto alloc = [&](size_t bytes) -> void* {
    void* p = ws + o;
    o += (bytes + 255) & ~(size_t)255;
    return p;
  };
  __bf16* WvT   = (__bf16*)alloc((size_t)HID * HID * 2);
  __bf16* WdxT  = (__bf16*)alloc((size_t)HID * IND * 2);
  float* h_tr   = (float*)alloc((size_t)N_ * HID * 4);
  float* lap1d  = (float*)alloc((size_t)N_ * HID * 4);
  __bf16* zb    = (__bf16*)alloc((size_t)N_ * HID * 2);
  float* dinv   = (float*)alloc((size_t)N_ * 4);
  int*   csrRow = (int*)alloc((size_t)N_ * CAP * 4);
  int*   zero0  = (int*)alloc((size_t)(2 * N_ + 65) * 4);
  int*   degRow = zero0;
  int*   cntCol = zero0 + N_;
  float* gsum   = (float*)(zero0 + 2 * N_);

  const int* row = ei;
  const int* col = ei + E_;

  (void)hipMemsetAsync(zero0, 0, (size_t)(2 * N_ + 65) * 4, stream);

  fused_front_kernel<<<1154, 256, 0, stream>>>(x_ori, x_train, row, col,
                                               W1, b1, W2, b2, Wv, Wdx, mask,
                                               WvT, WdxT, h_tr, gsum,
                                               degRow, cntCol, csrRow);
  lap1_kernel<<<N_ / 16, 256, 0, stream>>>(h_tr, degRow, cntCol, csrRow,
                                           lap1d, dinv);

  float* outp = (float*)d_out;
  lap2_attnz_xhat_kernel<<<N_ / 32, 512, 0, stream>>>(h_tr, lap1d, dinv,
                                                      cntCol, csrRow, gsum,
                                                      Wq, bq, Wk, bk, WvT, bv,
                                                      WdxT, bdx, outp, zb);
  adj_mfma_kernel<<<dim3(96, 96), 256, 0, stream>>>(zb, outp + (size_t)N_ * IND);
}